// Round 3
// baseline (7846.515 us; speedup 1.0000x reference)
//
#include <hip/hip_runtime.h>
#include <hip/hip_bf16.h>
#include <cstdint>
#include <cstddef>

#define VOCABN 10000
#define FEATC 512
#define EMBN 256
#define HIDN 512
#define AFFN 512
#define BB 32
#define TTN 60
#define PPN 196

using bf16 = __hip_bfloat16;

typedef __attribute__((ext_vector_type(8))) short short8;
typedef __attribute__((ext_vector_type(4))) float f32x4;

__device__ __forceinline__ float b2f(bf16 x){ return __bfloat162float(x); }
__device__ __forceinline__ float fexp2(float x){ return __builtin_amdgcn_exp2f(x); }
__device__ __forceinline__ float frcp(float x){ return __builtin_amdgcn_rcpf(x); }
__device__ __forceinline__ float fsig(float x){ return frcp(1.f + fexp2(-1.4426950408889634f*x)); }
__device__ __forceinline__ float ftanhf(float x){ return 1.f - 2.f*frcp(1.f + fexp2(2.8853900817779268f*x)); }

// read raw input element i as bf16-rounded f32 (input may be f32 or bf16 per flag)
__device__ __forceinline__ float rnd_read(const void* p, size_t i, bool f32){
  if (f32) return b2f(__float2bfloat16(((const float*)p)[i]));
  return b2f(((const bf16*)p)[i]);
}

// ---------- dtype probe ----------
__global__ void __launch_bounds__(256) k_probe(const uint32_t* __restrict__ w, int* __restrict__ flag){
  __shared__ int s;
  if (threadIdx.x == 0) s = 0;
  __syncthreads();
  int hit = 0;
  for (int i = threadIdx.x; i < 32768; i += 256){
    uint32_t v = w[i];
    if (((v & 0x7F800000u) == 0x7F800000u) || ((v & 0x00007F80u) == 0x00007F80u)) hit = 1;
  }
  if (hit) atomicOr(&s, 1);
  __syncthreads();
  if (threadIdx.x == 0) flag[0] = s;
}

// ---------- canonicalize tensor to bf16 ----------
__global__ void __launch_bounds__(256) k_cvt(const void* __restrict__ src, bf16* __restrict__ dst,
                                             int nquad, const int* __restrict__ flag){
  bool f32 = flag[0] != 0;
  int stride = gridDim.x * 256;
  for (int i = blockIdx.x*256 + threadIdx.x; i < nquad; i += stride){
    if (f32){
      float4 v = reinterpret_cast<const float4*>(src)[i];
      bf16* d = dst + 4*(size_t)i;
      d[0] = __float2bfloat16(v.x); d[1] = __float2bfloat16(v.y);
      d[2] = __float2bfloat16(v.z); d[3] = __float2bfloat16(v.w);
    } else {
      reinterpret_cast<uint2*>(dst)[i] = reinterpret_cast<const uint2*>(src)[i];
    }
  }
}

// ---------- prep: WkT4F[(k>>2)*2048 + a*4 + (k&3)] = rnd(Wk[a][k]) ----------
__global__ void __launch_bounds__(256) k_prep_wk(const void* __restrict__ src, const int* __restrict__ flag,
                                                 float* __restrict__ WkT4F){
  bool f32 = flag[0] != 0;
  int gid = blockIdx.x*256 + threadIdx.x;
  if (gid < AFFN*HIDN){
    int a = gid >> 9, k = gid & 511;
    WkT4F[(k>>2)*2048 + a*4 + (k&3)] = rnd_read(src, gid, f32);
  }
}

// ---------- prep: WgF[row][0..768)=Wih, [768..1280)=Whh (f32, bf16-rounded) ----------
__global__ void __launch_bounds__(256) k_prep_wg(const void* __restrict__ WihRaw, const void* __restrict__ WhhRaw,
                                                 const int* __restrict__ flag, float* __restrict__ WgF){
  bool f32 = flag[0] != 0;
  int total = 2048*1280;
  for (int gid = blockIdx.x*256 + threadIdx.x; gid < total; gid += gridDim.x*256){
    int row = gid / 1280, k = gid - row*1280;
    float v = (k < 768) ? rnd_read(WihRaw, (size_t)row*768 + k, f32)
                        : rnd_read(WhhRaw, (size_t)row*512 + (k-768), f32);
    WgF[gid] = v;
  }
}

// ---------- prep: bgF = bih+bhh ; waF ----------
__global__ void __launch_bounds__(256) k_prep_misc(const void* __restrict__ bihRaw, const void* __restrict__ bhhRaw,
                                                   const void* __restrict__ waRaw, const int* __restrict__ flag,
                                                   float* __restrict__ bgF, float* __restrict__ waF){
  bool f32 = flag[0] != 0;
  int gid = blockIdx.x*256 + threadIdx.x;
  if (gid < 2048) bgF[gid] = rnd_read(bihRaw, gid, f32) + rnd_read(bhhRaw, gid, f32);
  if (gid < 512)  waF[gid] = rnd_read(waRaw, gid, f32);
}

// ---------- precompute: feats[b][p][c] = rnd(cnn[b][c][p]) (bf16) ----------
__global__ void __launch_bounds__(256) k_transpose(const void* __restrict__ cnnRaw, const int* __restrict__ flag,
                                                   bf16* __restrict__ feats){
  __shared__ bf16 tile[32][34];
  bool f32 = flag[0] != 0;
  int ct = blockIdx.x, pt = blockIdx.y, b = blockIdx.z;
  int tid = threadIdx.x;
  int lc = tid >> 5, lp = tid & 31;
  int p = pt*32 + lp;
  #pragma unroll
  for (int i=0;i<4;i++){
    int cc = ct*32 + lc + i*8;
    float v = 0.f;
    if (p < PPN) v = rnd_read(cnnRaw, ((size_t)b*FEATC + cc)*PPN + p, f32);
    tile[lc + i*8][lp] = __float2bfloat16(v);
  }
  __syncthreads();
  #pragma unroll
  for (int i=0;i<4;i++){
    int pp = pt*32 + lc + i*8;
    if (pp < PPN) feats[((size_t)b*PPN + pp)*FEATC + ct*32 + lp] = tile[lp][lc + i*8];
  }
}

// ---------- precompute: g = mean ; h0,c0 ; also seed xT2 h-region (parity 0) ----------
__global__ void __launch_bounds__(256) k_init(const void* __restrict__ cnnRaw,
      const void* __restrict__ WhRaw, const void* __restrict__ bhRaw,
      const void* __restrict__ WcRaw, const void* __restrict__ bcRaw,
      const int* __restrict__ flag,
      float* __restrict__ h, float* __restrict__ c, float* __restrict__ xT2){
  __shared__ float gl[FEATC];
  bool f32 = flag[0] != 0;
  int b = blockIdx.x, tid = threadIdx.x;
  for (int cc = tid; cc < FEATC; cc += 256){
    size_t base = ((size_t)b*FEATC + cc)*PPN;
    float acc = 0.f;
    for (int p=0;p<PPN;p++) acc += rnd_read(cnnRaw, base+p, f32);
    gl[cc] = acc * (1.0f/196.0f);
  }
  __syncthreads();
  for (int i = tid; i < HIDN; i += 256){
    float a1=0.f, a2=0.f;
    for (int k=0;k<FEATC;k++){
      float gv = gl[k];
      a1 = fmaf(rnd_read(WhRaw, (size_t)i*FEATC+k, f32), gv, a1);
      a2 = fmaf(rnd_read(WcRaw, (size_t)i*FEATC+k, f32), gv, a2);
    }
    a1 += rnd_read(bhRaw, i, f32);
    a2 += rnd_read(bcRaw, i, f32);
    h[b*HIDN+i] = a1;
    c[b*HIDN+i] = a2;
    int k = 768 + i;
    xT2[(k>>2)*128 + b*4 + (k&3)] = a1;
  }
}

// ---------- generic MFMA GEMM: C[M][N] = A[M][K] @ Bw[N][K]^T (+bias) ----------
template<int OUTMODE, bool BIAS>
__global__ void __launch_bounds__(256) gemm_bt(const bf16* __restrict__ A, const bf16* __restrict__ Bw,
        const bf16* __restrict__ bias, void* __restrict__ Cout, int M, int N, int K,
        const int* __restrict__ flag){
  __shared__ __align__(16) bf16 As[64][40];
  __shared__ __align__(16) bf16 Bs[64][40];
  int tid = threadIdx.x;
  int m0 = blockIdx.y*64, n0 = blockIdx.x*64;
  int lr = tid >> 2;
  int lk = (tid & 3)*8;
  int wave = tid >> 6, lane = tid & 63;
  int ml = lane & 15, kg = lane >> 4;
  f32x4 acc0 = {0.f,0.f,0.f,0.f}, acc1 = acc0, acc2 = acc0, acc3 = acc0;
  for (int k0=0; k0<K; k0+=32){
    __syncthreads();
    {
      uint4 av = *reinterpret_cast<const uint4*>(A + (size_t)(m0+lr)*K + k0 + lk);
      *reinterpret_cast<uint4*>(&As[lr][lk]) = av;
      uint4 bv = make_uint4(0u,0u,0u,0u);
      int bn = n0 + lr;
      if (bn < N) bv = *reinterpret_cast<const uint4*>(Bw + (size_t)bn*K + k0 + lk);
      *reinterpret_cast<uint4*>(&Bs[lr][lk]) = bv;
    }
    __syncthreads();
    short8 af = *reinterpret_cast<const short8*>(&As[wave*16 + ml][kg*8]);
    short8 b0 = *reinterpret_cast<const short8*>(&Bs[ 0 + ml][kg*8]);
    short8 b1 = *reinterpret_cast<const short8*>(&Bs[16 + ml][kg*8]);
    short8 b2 = *reinterpret_cast<const short8*>(&Bs[32 + ml][kg*8]);
    short8 b3 = *reinterpret_cast<const short8*>(&Bs[48 + ml][kg*8]);
    acc0 = __builtin_amdgcn_mfma_f32_16x16x32_bf16(af, b0, acc0, 0,0,0);
    acc1 = __builtin_amdgcn_mfma_f32_16x16x32_bf16(af, b1, acc1, 0,0,0);
    acc2 = __builtin_amdgcn_mfma_f32_16x16x32_bf16(af, b2, acc2, 0,0,0);
    acc3 = __builtin_amdgcn_mfma_f32_16x16x32_bf16(af, b3, acc3, 0,0,0);
  }
  bool of32 = (OUTMODE == 0) ? true : (flag[0] != 0);
  int mb = m0 + wave*16 + (lane>>4)*4;
  int cl = lane & 15;
  f32x4 av[4] = {acc0, acc1, acc2, acc3};
  #pragma unroll
  for (int j=0;j<4;j++){
    int n = n0 + j*16 + cl;
    if (n < N){
      float bv = BIAS ? b2f(bias[n]) : 0.f;
      #pragma unroll
      for (int rr=0; rr<4; rr++){
        float v = av[j][rr] + bv;
        if (of32) ((float*)Cout)[(size_t)(mb+rr)*N + n] = v;
        else      ((bf16*)Cout)[(size_t)(mb+rr)*N + n] = __float2bfloat16(v);
      }
    }
  }
}

// ================= persistent recurrence kernel =================
// grid = 256 blocks x 512 threads (2048 waves << 8192 wave capacity -> co-resident)
// block (b = blk>>3, s = blk&7). 2 grid barriers/step + 3 per-batch mini-barriers.
__global__ void __launch_bounds__(512) k_recur(
    const float* __restrict__ WkT4F, const float* __restrict__ WgF,
    const float* __restrict__ bgF,  const float* __restrict__ waF,
    const float* __restrict__ kv,   const bf16* __restrict__ feats,
    float* __restrict__ h, float* __restrict__ c,
    float* __restrict__ hkG, float* __restrict__ zG, float* __restrict__ alphaG,
    float* __restrict__ xT2, bf16* __restrict__ Hb,
    const int* __restrict__ captions, const void* __restrict__ tableRaw,
    int* __restrict__ sync){
  __shared__ float hkL[512];
  __shared__ float part[64][9];
  __shared__ float alphaL[200];
  __shared__ float redL[16];
  __shared__ float gl[8][32];

  const int blk = blockIdx.x, tid = threadIdx.x;
  const int b = blk >> 3, s = blk & 7;
  const bool isf32 = sync[0] != 0;          // flag written by k_probe
  int* gcnt = sync + 1;
  int* hkd  = sync + 2;
  int* zd   = sync + 34;
  int* ad   = sync + 66;
  int bar = 0;

  const int lane = tid & 63, wv = tid >> 6;

  // z-phase per-lane constants
  const float4* wa4 = (const float4*)waF;
  float4 wv0 = wa4[lane*2], wv1 = wa4[lane*2+1];

  for (int t = 0; t < TTN; t++){
    // ---------------- Phase A: attention ----------------
    // A1: hk slice (this block computes a in [s*64, s*64+64), ksplit over waves)
    {
      int a = s*64 + lane;
      const float4* wk4 = (const float4*)WkT4F;
      const float4* hb4 = (const float4*)(h + b*HIDN);
      float acc = 0.f;
      #pragma unroll 4
      for (int it=0; it<16; it++){
        int k4 = wv*16 + it;
        float4 w = wk4[(size_t)k4*512 + a];
        float4 hv = hb4[k4];
        acc += w.x*hv.x + w.y*hv.y + w.z*hv.z + w.w*hv.w;
      }
      part[lane][wv] = acc;
    }
    __syncthreads();
    if (tid < 64){
      float v = 0.f;
      #pragma unroll
      for (int q=0;q<8;q++) v += part[tid][q];
      hkG[b*512 + s*64 + tid] = v;
    }
    __syncthreads();
    if (tid == 0){
      __hip_atomic_fetch_add(&hkd[b], 1, __ATOMIC_ACQ_REL, __HIP_MEMORY_SCOPE_AGENT);
      while (__hip_atomic_load(&hkd[b], __ATOMIC_ACQUIRE, __HIP_MEMORY_SCOPE_AGENT) < 8*(t+1)) ;
    }
    __syncthreads();
    hkL[tid] = hkG[b*512 + tid];
    __syncthreads();

    // A2: z for p-slice [s*25, min(s*25+25,196))
    {
      float4 hk0 = *(const float4*)&hkL[lane*8];
      float4 hk1 = *(const float4*)&hkL[lane*8+4];
      int p0 = s*25;
      int pend = p0 + 25; if (pend > PPN) pend = PPN;
      for (int p = p0 + wv; p < pend; p += 8){
        const float4* kp = (const float4*)(kv + ((size_t)(b*PPN+p))*512 + lane*8);
        float4 k0 = kp[0], k1 = kp[1];
        float acc;
        acc  = wv0.x*ftanhf(k0.x+hk0.x);
        acc += wv0.y*ftanhf(k0.y+hk0.y);
        acc += wv0.z*ftanhf(k0.z+hk0.z);
        acc += wv0.w*ftanhf(k0.w+hk0.w);
        acc += wv1.x*ftanhf(k1.x+hk1.x);
        acc += wv1.y*ftanhf(k1.y+hk1.y);
        acc += wv1.z*ftanhf(k1.z+hk1.z);
        acc += wv1.w*ftanhf(k1.w+hk1.w);
        #pragma unroll
        for (int d=1; d<64; d<<=1) acc += __shfl_xor(acc, d, 64);
        if (lane == 0) zG[b*256 + p] = acc;
      }
    }
    __syncthreads();
    if (tid == 0){
      __hip_atomic_fetch_add(&zd[b], 1, __ATOMIC_ACQ_REL, __HIP_MEMORY_SCOPE_AGENT);
      if (s == 0)
        while (__hip_atomic_load(&zd[b], __ATOMIC_ACQUIRE, __HIP_MEMORY_SCOPE_AGENT) < 8*(t+1)) ;
    }
    __syncthreads();

    // A3: softmax (leader s==0), publish alpha
    if (s == 0){
      float v = (tid < PPN) ? zG[b*256 + tid] : -3.0e38f;
      float m = v;
      #pragma unroll
      for (int d=1; d<64; d<<=1) m = fmaxf(m, __shfl_xor(m, d, 64));
      if (lane == 0) redL[wv] = m;
      __syncthreads();
      float mx = redL[0];
      #pragma unroll
      for (int q=1;q<8;q++) mx = fmaxf(mx, redL[q]);
      float e = (tid < PPN) ? fexp2((v - mx)*1.4426950408889634f) : 0.f;
      float ss = e;
      #pragma unroll
      for (int d=1; d<64; d<<=1) ss += __shfl_xor(ss, d, 64);
      if (lane == 0) redL[8+wv] = ss;
      __syncthreads();
      float tot = redL[8];
      #pragma unroll
      for (int q=1;q<8;q++) tot += redL[8+q];
      float a = e / tot;
      if (tid < PPN){ alphaG[b*256 + tid] = a; alphaL[tid] = a; }
      __syncthreads();
      if (tid == 0)
        __hip_atomic_store(&ad[b], t+1, __ATOMIC_RELEASE, __HIP_MEMORY_SCOPE_AGENT);
    } else {
      if (tid == 0)
        while (__hip_atomic_load(&ad[b], __ATOMIC_ACQUIRE, __HIP_MEMORY_SCOPE_AGENT) < t+1) ;
      __syncthreads();
      if (tid < PPN) alphaL[tid] = alphaG[b*256 + tid];
    }
    __syncthreads();

    // A4: ctx slice c in [s*64, s*64+64)
    {
      int cc = tid & 63, ps = tid >> 6;
      int p0 = ps*25, pend = p0 + 25; if (pend > PPN) pend = PPN;
      const bf16* fb = feats + (size_t)b*PPN*FEATC + s*64 + cc;
      float acc = 0.f;
      for (int p = p0; p < pend; p++)
        acc = fmaf(alphaL[p], b2f(fb[(size_t)p*FEATC]), acc);
      part[cc][ps] = acc;
    }
    __syncthreads();
    if (tid < 64){
      float v = 0.f;
      #pragma unroll
      for (int q=0;q<8;q++) v += part[tid][q];
      int k = 256 + s*64 + tid;
      xT2[(k>>2)*128 + b*4 + (k&3)] = v;
    }
    // A5: emb for step t (block s==7)
    if (s == 7 && tid < EMBN){
      int tok = captions[b*TTN + t];
      float v = rnd_read(tableRaw, (size_t)tok*EMBN + tid, isf32);
      xT2[(tid>>2)*128 + b*4 + (tid&3)] = v;
    }
    bar++; 
    __syncthreads();
    if (tid == 0){
      __hip_atomic_fetch_add(gcnt, 1, __ATOMIC_ACQ_REL, __HIP_MEMORY_SCOPE_AGENT);
      while (__hip_atomic_load(gcnt, __ATOMIC_ACQUIRE, __HIP_MEMORY_SCOPE_AGENT) < 256*bar)
        __builtin_amdgcn_s_sleep(1);
    }
    __syncthreads();

    // ---------------- Phase B: gates + LSTM cell ----------------
    {
      int bb = lane >> 1, khalf = lane & 1;
      int gate = wv & 3, jj = wv >> 2;
      int row = gate*HIDN + blk*2 + jj;
      const float4* wr = (const float4*)(WgF + (size_t)row*1280);
      const float4* xt = (const float4*)xT2;
      int hoffs = (t & 1) * 128;
      float a0=0.f,a1=0.f,a2=0.f,a3=0.f;
      #pragma unroll 4
      for (int it=0; it<160; it++){
        int k4 = khalf*160 + it;
        float4 wvv = wr[k4];
        int keff4 = (k4 < 192) ? k4 : k4 + hoffs;
        float4 xv = xt[keff4*32 + bb];
        a0 = fmaf(wvv.x, xv.x, a0); a1 = fmaf(wvv.y, xv.y, a1);
        a2 = fmaf(wvv.z, xv.z, a2); a3 = fmaf(wvv.w, xv.w, a3);
      }
      float a = (a0+a1)+(a2+a3);
      a += __shfl_xor(a, 1, 64);
      if (khalf == 0) gl[wv][bb] = a + bgF[row];
    }
    __syncthreads();
    if (tid < 64){
      int bb = tid & 31, j2 = tid >> 5;
      int j = blk*2 + j2;
      float gi = gl[j2*4+0][bb], gf = gl[j2*4+1][bb];
      float gg = gl[j2*4+2][bb], go = gl[j2*4+3][bb];
      float cold = c[bb*HIDN + j];
      float cn = fsig(gf)*cold + fsig(gi)*ftanhf(gg);
      float hn = fsig(go)*ftanhf(cn);
      c[bb*HIDN + j] = cn;
      h[bb*HIDN + j] = hn;
      int k = 768 + j;
      int k4 = (k>>2) + ((t+1)&1)*128;
      xT2[k4*128 + bb*4 + (k&3)] = hn;
      Hb[((size_t)bb*TTN + t)*HIDN + j] = __float2bfloat16(hn);
    }
    bar++;
    __syncthreads();
    if (tid == 0){
      __hip_atomic_fetch_add(gcnt, 1, __ATOMIC_ACQ_REL, __HIP_MEMORY_SCOPE_AGENT);
      while (__hip_atomic_load(gcnt, __ATOMIC_ACQUIRE, __HIP_MEMORY_SCOPE_AGENT) < 256*bar)
        __builtin_amdgcn_s_sleep(1);
    }
    __syncthreads();
  }
}

static inline int cvt_grid(int nquad){ int g = (nquad + 255)/256; return g > 1024 ? 1024 : g; }

extern "C" void kernel_launch(void* const* d_in, const int* in_sizes, int n_in,
                              void* d_out, int out_size, void* d_ws, size_t ws_size,
                              hipStream_t stream) {
  const int* captions = (const int*)d_in[1];

  char* ws = (char*)d_ws;
  bf16*  feats = (bf16*) (ws);                 // [6272][512] bf16        6,422,528
  float* kv    = (float*)(ws + 6422528);       // [6272][512] f32        12,845,056
  float* h     = (float*)(ws + 19267584);      // [32][512] f32
  float* c     = (float*)(ws + 19333120);
  float* hkG   = (float*)(ws + 19398656);
  float* zG    = (float*)(ws + 19464192);      // [32][256]
  float* alphaG= (float*)(ws + 19496960);      // [32][256]
  float* xT2   = (float*)(ws + 19529728);      // [448 k4][32 b][4] f32    229,376
  bf16*  Hb    = (bf16*) (ws + 19759104);      // [32][60][512] bf16     1,966,080
  bf16*  WvB   = (bf16*) (ws + 21725184);      //                          524,288
  bf16*  WfcB  = (bf16*) (ws + 22249472);      //                       10,240,000
  bf16*  bfcB  = (bf16*) (ws + 32489472);      //                           20,000
  float* WkT4F = (float*)(ws + 32509472);      //                        1,048,576
  float* WgF   = (float*)(ws + 33558048);      // [2048][1280] f32      10,485,760
  float* bgF   = (float*)(ws + 44043808);      //                            8,192
  float* waF   = (float*)(ws + 44052000);      //                            2,048
  int*   syncA = (int*)  (ws + 44054048);      // flag + barrier counters    1,024
  if (ws_size < 44055072ull) return;

  // 0) zero sync area (counters are step-tagged monotonic; fresh zeros each call)
  hipMemsetAsync(syncA, 0, 1024, stream);

  // 1) dtype probe (embed_table is N(0,1): f32 low-half mantissa hits exp==0xFF)
  k_probe<<<1, 256, 0, stream>>>((const uint32_t*)d_in[5], syncA);

  // 2) weight prep
  k_prep_wk  <<<1024, 256, 0, stream>>>(d_in[2], syncA, WkT4F);
  k_prep_wg  <<<2048, 256, 0, stream>>>(d_in[10], d_in[11], syncA, WgF);
  k_prep_misc<<<8,    256, 0, stream>>>(d_in[12], d_in[13], d_in[4], syncA, bgF, waF);
  k_cvt<<<cvt_grid(65536),  256, 0, stream>>>(d_in[3],  WvB,  65536,  syncA);
  k_cvt<<<cvt_grid(1280000),256, 0, stream>>>(d_in[14], WfcB, 1280000, syncA);
  k_cvt<<<cvt_grid(2500),   256, 0, stream>>>(d_in[15], bfcB, 2500,   syncA);

  // 3) precompute
  k_transpose<<<dim3(16,7,32), 256, 0, stream>>>(d_in[0], syncA, feats);
  k_init<<<32, 256, 0, stream>>>(d_in[0], d_in[6], d_in[7], d_in[8], d_in[9], syncA, h, c, xT2);
  gemm_bt<0,false><<<dim3(8,98), 256, 0, stream>>>(feats, WvB, (const bf16*)nullptr, (void*)kv,
                                                   6272, 512, 512, (const int*)nullptr);

  // 4) persistent recurrence (256 blocks x 512 thr = 2048 waves, 1/4 of capacity)
  k_recur<<<256, 512, 0, stream>>>(WkT4F, WgF, bgF, waF, kv, feats, h, c,
                                   hkG, zG, alphaG, xT2, Hb, captions, d_in[5], syncA);

  // 5) logits = Hb @ Wfc^T + bfc
  gemm_bt<1,true><<<dim3(157,30), 256, 0, stream>>>(Hb, WfcB, bfcB, d_out,
                                                    1920, 10000, 512, syncA);
}

// Round 4
// 7538.121 us; speedup vs baseline: 1.0409x; 1.0409x over previous
//
#include <hip/hip_runtime.h>
#include <hip/hip_bf16.h>
#include <cstdint>
#include <cstddef>

#define VOCABN 10000
#define FEATC 512
#define EMBN 256
#define HIDN 512
#define AFFN 512
#define BB 32
#define TTN 60
#define PPN 196

using bf16 = __hip_bfloat16;

typedef __attribute__((ext_vector_type(8))) short short8;
typedef __attribute__((ext_vector_type(4))) float f32x4;

__device__ __forceinline__ float b2f(bf16 x){ return __bfloat162float(x); }
__device__ __forceinline__ float fexp2(float x){ return __builtin_amdgcn_exp2f(x); }
__device__ __forceinline__ float frcp(float x){ return __builtin_amdgcn_rcpf(x); }
__device__ __forceinline__ float fsig(float x){ return frcp(1.f + fexp2(-1.4426950408889634f*x)); }
__device__ __forceinline__ float ftanhf(float x){ return 1.f - 2.f*frcp(1.f + fexp2(2.8853900817779268f*x)); }

// read raw input element i as bf16-rounded f32 (input may be f32 or bf16 per flag)
__device__ __forceinline__ float rnd_read(const void* p, size_t i, bool f32){
  if (f32) return b2f(__float2bfloat16(((const float*)p)[i]));
  return b2f(((const bf16*)p)[i]);
}

// ---------- dtype probe ----------
__global__ void __launch_bounds__(256) k_probe(const uint32_t* __restrict__ w, int* __restrict__ flag){
  __shared__ int s;
  if (threadIdx.x == 0) s = 0;
  __syncthreads();
  int hit = 0;
  for (int i = threadIdx.x; i < 32768; i += 256){
    uint32_t v = w[i];
    if (((v & 0x7F800000u) == 0x7F800000u) || ((v & 0x00007F80u) == 0x00007F80u)) hit = 1;
  }
  if (hit) atomicOr(&s, 1);
  __syncthreads();
  if (threadIdx.x == 0) flag[0] = s;
}

// ---------- merged prep: all weight repacks + bf16 conversions in ONE launch ----------
struct PrepArgs {
  const void *wk, *wih, *whh, *bih, *bhh, *wa, *wv, *wfc, *bfc;
  float *WkT4F, *WgF, *bgF, *waF;
  bf16 *WvB, *WfcB, *bfcB;
};

__device__ __forceinline__ void cvt4(const void* src, bf16* dst, int i, int n, bool f32){
  if (i >= n) return;
  if (f32){
    float4 v = reinterpret_cast<const float4*>(src)[i];
    bf16* d = dst + 4*(size_t)i;
    d[0]=__float2bfloat16(v.x); d[1]=__float2bfloat16(v.y);
    d[2]=__float2bfloat16(v.z); d[3]=__float2bfloat16(v.w);
  } else {
    reinterpret_cast<uint2*>(dst)[i] = reinterpret_cast<const uint2*>(src)[i];
  }
}

__global__ void __launch_bounds__(256) k_prep(PrepArgs a, const int* __restrict__ flag){
  bool f32 = flag[0] != 0;
  int blk = blockIdx.x, tid = threadIdx.x;
  if (blk < 1024){                       // WkT4F[(k>>2)*2048 + a*4 + (k&3)] = Wk[a][k]
    int gid = blk*256 + tid;             // 262144 exact
    int aa = gid >> 9, k = gid & 511;
    a.WkT4F[(k>>2)*2048 + aa*4 + (k&3)] = rnd_read(a.wk, gid, f32);
  } else if (blk < 3072){                // WgF[row][0..768)=Wih, [768..1280)=Whh
    for (int gid = (blk-1024)*256 + tid; gid < 2048*1280; gid += 2048*256){
      int row = gid / 1280, k = gid - row*1280;
      a.WgF[gid] = (k < 768) ? rnd_read(a.wih, (size_t)row*768 + k, f32)
                             : rnd_read(a.whh, (size_t)row*512 + (k-768), f32);
    }
  } else if (blk < 3080){                // bg = bih+bhh ; wa
    int gid = (blk-3072)*256 + tid;
    if (gid < 2048) a.bgF[gid] = rnd_read(a.bih, gid, f32) + rnd_read(a.bhh, gid, f32);
    if (gid < 512)  a.waF[gid] = rnd_read(a.wa, gid, f32);
  } else if (blk < 3336){                // Wv -> bf16 (65536 quads exact)
    cvt4(a.wv, a.WvB, (blk-3080)*256 + tid, 65536, f32);
  } else if (blk < 4360){                // Wfc -> bf16 (1.28M quads, 5 strides)
    for (int i = (blk-3336)*256 + tid; i < 1280000; i += 1024*256)
      cvt4(a.wfc, a.WfcB, i, 1280000, f32);
  } else {                               // bfc -> bf16 (2500 quads)
    cvt4(a.bfc, a.bfcB, (blk-4360)*256 + tid, 2500, f32);
  }
}

// ---------- precompute: feats[b][p][c] = rnd(cnn[b][c][p]) (bf16) ----------
__global__ void __launch_bounds__(256) k_transpose(const void* __restrict__ cnnRaw, const int* __restrict__ flag,
                                                   bf16* __restrict__ feats){
  __shared__ bf16 tile[32][34];
  bool f32 = flag[0] != 0;
  int ct = blockIdx.x, pt = blockIdx.y, b = blockIdx.z;
  int tid = threadIdx.x;
  int lc = tid >> 5, lp = tid & 31;
  int p = pt*32 + lp;
  #pragma unroll
  for (int i=0;i<4;i++){
    int cc = ct*32 + lc + i*8;
    float v = 0.f;
    if (p < PPN) v = rnd_read(cnnRaw, ((size_t)b*FEATC + cc)*PPN + p, f32);
    tile[lc + i*8][lp] = __float2bfloat16(v);
  }
  __syncthreads();
  #pragma unroll
  for (int i=0;i<4;i++){
    int pp = pt*32 + lc + i*8;
    if (pp < PPN) feats[((size_t)b*PPN + pp)*FEATC + ct*32 + lp] = tile[lp][lc + i*8];
  }
}

// ---------- precompute: g = mean ; h0,c0 ; seed xT2 h-region (parity 0) ----------
__global__ void __launch_bounds__(256) k_init(const void* __restrict__ cnnRaw,
      const void* __restrict__ WhRaw, const void* __restrict__ bhRaw,
      const void* __restrict__ WcRaw, const void* __restrict__ bcRaw,
      const int* __restrict__ flag,
      float* __restrict__ h, float* __restrict__ c, float* __restrict__ xT2){
  __shared__ float gl[FEATC];
  bool f32 = flag[0] != 0;
  int b = blockIdx.x, tid = threadIdx.x;
  for (int cc = tid; cc < FEATC; cc += 256){
    size_t base = ((size_t)b*FEATC + cc)*PPN;
    float acc = 0.f;
    for (int p=0;p<PPN;p++) acc += rnd_read(cnnRaw, base+p, f32);
    gl[cc] = acc * (1.0f/196.0f);
  }
  __syncthreads();
  for (int i = tid; i < HIDN; i += 256){
    float a1=0.f, a2=0.f;
    for (int k=0;k<FEATC;k++){
      float gv = gl[k];
      a1 = fmaf(rnd_read(WhRaw, (size_t)i*FEATC+k, f32), gv, a1);
      a2 = fmaf(rnd_read(WcRaw, (size_t)i*FEATC+k, f32), gv, a2);
    }
    a1 += rnd_read(bhRaw, i, f32);
    a2 += rnd_read(bcRaw, i, f32);
    h[b*HIDN+i] = a1;
    c[b*HIDN+i] = a2;
    int k = 768 + i;
    xT2[(k>>2)*128 + b*4 + (k&3)] = a1;   // parity-0 h region
  }
}

// ---------- generic MFMA GEMM: C[M][N] = A[M][K] @ Bw[N][K]^T (+bias) ----------
template<int OUTMODE, bool BIAS>
__global__ void __launch_bounds__(256) gemm_bt(const bf16* __restrict__ A, const bf16* __restrict__ Bw,
        const bf16* __restrict__ bias, void* __restrict__ Cout, int M, int N, int K,
        const int* __restrict__ flag){
  __shared__ __align__(16) bf16 As[64][40];
  __shared__ __align__(16) bf16 Bs[64][40];
  int tid = threadIdx.x;
  int m0 = blockIdx.y*64, n0 = blockIdx.x*64;
  int lr = tid >> 2;
  int lk = (tid & 3)*8;
  int wave = tid >> 6, lane = tid & 63;
  int ml = lane & 15, kg = lane >> 4;
  f32x4 acc0 = {0.f,0.f,0.f,0.f}, acc1 = acc0, acc2 = acc0, acc3 = acc0;
  for (int k0=0; k0<K; k0+=32){
    __syncthreads();
    {
      uint4 av = *reinterpret_cast<const uint4*>(A + (size_t)(m0+lr)*K + k0 + lk);
      *reinterpret_cast<uint4*>(&As[lr][lk]) = av;
      uint4 bv = make_uint4(0u,0u,0u,0u);
      int bn = n0 + lr;
      if (bn < N) bv = *reinterpret_cast<const uint4*>(Bw + (size_t)bn*K + k0 + lk);
      *reinterpret_cast<uint4*>(&Bs[lr][lk]) = bv;
    }
    __syncthreads();
    short8 af = *reinterpret_cast<const short8*>(&As[wave*16 + ml][kg*8]);
    short8 b0 = *reinterpret_cast<const short8*>(&Bs[ 0 + ml][kg*8]);
    short8 b1 = *reinterpret_cast<const short8*>(&Bs[16 + ml][kg*8]);
    short8 b2 = *reinterpret_cast<const short8*>(&Bs[32 + ml][kg*8]);
    short8 b3 = *reinterpret_cast<const short8*>(&Bs[48 + ml][kg*8]);
    acc0 = __builtin_amdgcn_mfma_f32_16x16x32_bf16(af, b0, acc0, 0,0,0);
    acc1 = __builtin_amdgcn_mfma_f32_16x16x32_bf16(af, b1, acc1, 0,0,0);
    acc2 = __builtin_amdgcn_mfma_f32_16x16x32_bf16(af, b2, acc2, 0,0,0);
    acc3 = __builtin_amdgcn_mfma_f32_16x16x32_bf16(af, b3, acc3, 0,0,0);
  }
  bool of32 = (OUTMODE == 0) ? true : (flag[0] != 0);
  int mb = m0 + wave*16 + (lane>>4)*4;
  int cl = lane & 15;
  f32x4 av[4] = {acc0, acc1, acc2, acc3};
  #pragma unroll
  for (int j=0;j<4;j++){
    int n = n0 + j*16 + cl;
    if (n < N){
      float bv = BIAS ? b2f(bias[n]) : 0.f;
      #pragma unroll
      for (int rr=0; rr<4; rr++){
        float v = av[j][rr] + bv;
        if (of32) ((float*)Cout)[(size_t)(mb+rr)*N + n] = v;
        else      ((bf16*)Cout)[(size_t)(mb+rr)*N + n] = __float2bfloat16(v);
      }
    }
  }
}

// ================= persistent recurrence kernel =================
// 256 blocks x 512 thr (2048 waves, 1 block/CU). Block = (b=blk>>3, s=blk&7).
// Barriers: flag store+poll (NO atomic RMW — R3's fetch_add barrier cost ~38us
// from 256 serialized cross-XCD RMWs on one line; flags arrive in parallel).
__global__ void __launch_bounds__(512) k_recur(
    const float* __restrict__ WkT4F, const float* __restrict__ WgF,
    const float* __restrict__ bgF,  const float* __restrict__ waF,
    const float* __restrict__ kv,   const bf16* __restrict__ feats,
    float* __restrict__ h, float* __restrict__ c,
    float* __restrict__ hkG, float* __restrict__ zG,
    float* __restrict__ xT2, bf16* __restrict__ Hb,
    const int* __restrict__ captions, const void* __restrict__ tableRaw,
    int* __restrict__ sync){
  __shared__ float hkL[512];
  __shared__ float part[64][9];
  __shared__ float alphaL[200];
  __shared__ float redL[16];
  __shared__ float gl[8][32];

  const int blk = blockIdx.x, tid = threadIdx.x;
  const int b = blk >> 3, s = blk & 7;
  const bool isf32 = sync[0] != 0;
  int* AG1 = sync + 16;     // 256 flags: end-of-step (h ready)
  int* AG2 = sync + 272;    // 256 flags: x ready
  int* PB1 = sync + 528;    // 32 x 16 (line-padded): hk ready
  int* PB2 = sync + 1040;   // 32 x 16: z ready

  const int lane = tid & 63, wv = tid >> 6;
  const float4* wa4 = (const float4*)waF;
  float4 wv0 = wa4[lane*2], wv1 = wa4[lane*2+1];

  for (int t = 0; t < TTN; t++){
    const int gen = t + 1;

    // ---- A1: hk slice (a in [s*64,s*64+64), k split over 8 waves) ----
    {
      int aa = s*64 + lane;
      const float4* wk4 = (const float4*)WkT4F;
      const float4* hb4 = (const float4*)(h + b*HIDN);
      float acc = 0.f;
      #pragma unroll 4
      for (int it=0; it<16; it++){
        int k4 = wv*16 + it;
        float4 w = wk4[(size_t)k4*512 + aa];
        float4 hv = hb4[k4];
        acc += w.x*hv.x + w.y*hv.y + w.z*hv.z + w.w*hv.w;
      }
      part[lane][wv] = acc;
    }
    __syncthreads();
    if (tid < 64){
      float v = 0.f;
      #pragma unroll
      for (int q=0;q<8;q++) v += part[tid][q];
      hkG[b*512 + s*64 + tid] = v;
    }
    // ---- P1: per-batch barrier (hk ready) ----
    __syncthreads();
    if (tid == 0) __hip_atomic_store(&PB1[b*16+s], gen, __ATOMIC_RELEASE, __HIP_MEMORY_SCOPE_AGENT);
    { int ok;
      do { ok = (tid < 8) ? (__hip_atomic_load(&PB1[b*16+tid], __ATOMIC_ACQUIRE, __HIP_MEMORY_SCOPE_AGENT) >= gen) : 1; }
      while (__syncthreads_count(ok) < 512); }
    hkL[tid] = hkG[b*512 + tid];
    __syncthreads();

    // ---- A2: z for p-slice [s*25, min(s*25+25,196)) ----
    {
      float4 hk0 = *(const float4*)&hkL[lane*8];
      float4 hk1 = *(const float4*)&hkL[lane*8+4];
      int p0 = s*25;
      int pend = p0 + 25; if (pend > PPN) pend = PPN;
      for (int p = p0 + wv; p < pend; p += 8){
        const float4* kp = (const float4*)(kv + ((size_t)(b*PPN+p))*512 + lane*8);
        float4 k0 = kp[0], k1 = kp[1];
        float acc;
        acc  = wv0.x*ftanhf(k0.x+hk0.x);
        acc += wv0.y*ftanhf(k0.y+hk0.y);
        acc += wv0.z*ftanhf(k0.z+hk0.z);
        acc += wv0.w*ftanhf(k0.w+hk0.w);
        acc += wv1.x*ftanhf(k1.x+hk1.x);
        acc += wv1.y*ftanhf(k1.y+hk1.y);
        acc += wv1.z*ftanhf(k1.z+hk1.z);
        acc += wv1.w*ftanhf(k1.w+hk1.w);
        #pragma unroll
        for (int d=1; d<64; d<<=1) acc += __shfl_xor(acc, d, 64);
        if (lane == 0) zG[b*256 + p] = acc;
      }
    }
    // ---- P2: per-batch barrier (z ready) ----
    __syncthreads();
    if (tid == 0) __hip_atomic_store(&PB2[b*16+s], gen, __ATOMIC_RELEASE, __HIP_MEMORY_SCOPE_AGENT);
    { int ok;
      do { ok = (tid < 8) ? (__hip_atomic_load(&PB2[b*16+tid], __ATOMIC_ACQUIRE, __HIP_MEMORY_SCOPE_AGENT) >= gen) : 1; }
      while (__syncthreads_count(ok) < 512); }

    // ---- A3: softmax, redundantly in EVERY block (no leader, no publish) ----
    {
      float v = (tid < PPN) ? zG[b*256 + tid] : -3.0e38f;
      float m = v;
      #pragma unroll
      for (int d=1; d<64; d<<=1) m = fmaxf(m, __shfl_xor(m, d, 64));
      if (lane == 0) redL[wv] = m;
      __syncthreads();
      float mx = redL[0];
      #pragma unroll
      for (int q=1;q<8;q++) mx = fmaxf(mx, redL[q]);
      float e = (tid < PPN) ? fexp2((v - mx)*1.4426950408889634f) : 0.f;
      float ss = e;
      #pragma unroll
      for (int d=1; d<64; d<<=1) ss += __shfl_xor(ss, d, 64);
      if (lane == 0) redL[8+wv] = ss;
      __syncthreads();
      float tot = redL[8];
      #pragma unroll
      for (int q=1;q<8;q++) tot += redL[8+q];
      if (tid < PPN) alphaL[tid] = e / tot;
    }
    __syncthreads();

    // ---- A4: ctx slice c in [s*64,s*64+64) -> xT2 ----
    {
      int cc = tid & 63, ps = tid >> 6;
      int p0 = ps*25, pend = p0 + 25; if (pend > PPN) pend = PPN;
      const bf16* fb = feats + (size_t)b*PPN*FEATC + s*64 + cc;
      float acc = 0.f;
      for (int p = p0; p < pend; p++)
        acc = fmaf(alphaL[p], b2f(fb[(size_t)p*FEATC]), acc);
      part[cc][ps] = acc;
    }
    __syncthreads();
    if (tid < 64){
      float v = 0.f;
      #pragma unroll
      for (int q=0;q<8;q++) v += part[tid][q];
      int k = 256 + s*64 + tid;
      xT2[(k>>2)*128 + b*4 + (k&3)] = v;
    }
    // ---- A5: emb for step t (block s==7) ----
    if (s == 7 && tid < EMBN){
      int tok = captions[b*TTN + t];
      float v = rnd_read(tableRaw, (size_t)tok*EMBN + tid, isf32);
      xT2[(tid>>2)*128 + b*4 + (tid&3)] = v;
    }
    // ---- G2: grid barrier (x ready; gate phase is cross-batch) ----
    __syncthreads();
    if (tid == 0) __hip_atomic_store(&AG2[blk], gen, __ATOMIC_RELEASE, __HIP_MEMORY_SCOPE_AGENT);
    { int ok;
      do { ok = (tid < 256) ? (__hip_atomic_load(&AG2[tid], __ATOMIC_ACQUIRE, __HIP_MEMORY_SCOPE_AGENT) >= gen) : 1; }
      while (__syncthreads_count(ok) < 512); }

    // ---- B: gates + LSTM cell (rows {g*512 + blk*2 + jj}, all batches via lanes) ----
    {
      int bb = lane >> 1, khalf = lane & 1;
      int gate = wv & 3, jj = wv >> 2;
      int row = gate*HIDN + blk*2 + jj;
      const float4* wr = (const float4*)(WgF + (size_t)row*1280);
      const float4* xt = (const float4*)xT2;
      int hoffs = (t & 1) * 128;
      float a0=0.f,a1=0.f,a2=0.f,a3=0.f;
      #pragma unroll 4
      for (int it=0; it<160; it++){
        int k4 = khalf*160 + it;
        float4 wvv = wr[k4];
        int keff4 = (k4 < 192) ? k4 : k4 + hoffs;
        float4 xv = xt[keff4*32 + bb];
        a0 = fmaf(wvv.x, xv.x, a0); a1 = fmaf(wvv.y, xv.y, a1);
        a2 = fmaf(wvv.z, xv.z, a2); a3 = fmaf(wvv.w, xv.w, a3);
      }
      float a = (a0+a1)+(a2+a3);
      a += __shfl_xor(a, 1, 64);
      if (khalf == 0) gl[wv][bb] = a + bgF[row];
    }
    __syncthreads();
    if (tid < 64){
      int bb = tid & 31, j2 = tid >> 5;
      int j = blk*2 + j2;
      float gi = gl[j2*4+0][bb], gf = gl[j2*4+1][bb];
      float gg = gl[j2*4+2][bb], go = gl[j2*4+3][bb];
      float cold = c[bb*HIDN + j];
      float cn = fsig(gf)*cold + fsig(gi)*ftanhf(gg);
      float hn = fsig(go)*ftanhf(cn);
      c[bb*HIDN + j] = cn;
      h[bb*HIDN + j] = hn;
      int k = 768 + j;
      int k4 = (k>>2) + ((t+1)&1)*128;
      xT2[k4*128 + bb*4 + (k&3)] = hn;
      Hb[((size_t)bb*TTN + t)*HIDN + j] = __float2bfloat16(hn);
    }
    // ---- G1: grid barrier (h ready for next step) ----
    __syncthreads();
    if (tid == 0) __hip_atomic_store(&AG1[blk], gen, __ATOMIC_RELEASE, __HIP_MEMORY_SCOPE_AGENT);
    { int ok;
      do { ok = (tid < 256) ? (__hip_atomic_load(&AG1[tid], __ATOMIC_ACQUIRE, __HIP_MEMORY_SCOPE_AGENT) >= gen) : 1; }
      while (__syncthreads_count(ok) < 512); }
  }
}

extern "C" void kernel_launch(void* const* d_in, const int* in_sizes, int n_in,
                              void* d_out, int out_size, void* d_ws, size_t ws_size,
                              hipStream_t stream) {
  const int* captions = (const int*)d_in[1];

  char* ws = (char*)d_ws;
  bf16*  feats = (bf16*) (ws);                 // [6272][512] bf16        6,422,528
  float* kv    = (float*)(ws + 6422528);       // [6272][512] f32        12,845,056
  float* h     = (float*)(ws + 19267584);      // [32][512] f32
  float* c     = (float*)(ws + 19333120);
  float* hkG   = (float*)(ws + 19398656);
  float* zG    = (float*)(ws + 19464192);      // [32][256]
  int*   syncA = (int*)  (ws + 19496960);      // flag + 4 barrier sites (8 KB)
  float* xT2   = (float*)(ws + 19529728);      // [448 k4][32 b][4] f32    229,376
  bf16*  Hb    = (bf16*) (ws + 19759104);      // [32][60][512] bf16     1,966,080
  bf16*  WvB   = (bf16*) (ws + 21725184);      //                          524,288
  bf16*  WfcB  = (bf16*) (ws + 22249472);      //                       10,240,000
  bf16*  bfcB  = (bf16*) (ws + 32489472);      //                           20,000
  float* WkT4F = (float*)(ws + 32509472);      //                        1,048,576
  float* WgF   = (float*)(ws + 33558048);      // [2048][1280] f32      10,485,760
  float* bgF   = (float*)(ws + 44043808);      //                            8,192
  float* waF   = (float*)(ws + 44052000);      //                            2,048
  if (ws_size < 44054048ull) return;

  hipMemsetAsync(syncA, 0, 8192, stream);
  k_probe<<<1, 256, 0, stream>>>((const uint32_t*)d_in[5], syncA);

  PrepArgs pa;
  pa.wk = d_in[2]; pa.wih = d_in[10]; pa.whh = d_in[11]; pa.bih = d_in[12];
  pa.bhh = d_in[13]; pa.wa = d_in[4]; pa.wv = d_in[3]; pa.wfc = d_in[14]; pa.bfc = d_in[15];
  pa.WkT4F = WkT4F; pa.WgF = WgF; pa.bgF = bgF; pa.waF = waF;
  pa.WvB = WvB; pa.WfcB = WfcB; pa.bfcB = bfcB;
  k_prep<<<4370, 256, 0, stream>>>(pa, syncA);

  k_transpose<<<dim3(16,7,32), 256, 0, stream>>>(d_in[0], syncA, feats);
  k_init<<<32, 256, 0, stream>>>(d_in[0], d_in[6], d_in[7], d_in[8], d_in[9], syncA, h, c, xT2);
  gemm_bt<0,false><<<dim3(8,98), 256, 0, stream>>>(feats, WvB, (const bf16*)nullptr, (void*)kv,
                                                   6272, 512, 512, (const int*)nullptr);

  k_recur<<<256, 512, 0, stream>>>(WkT4F, WgF, bgF, waF, kv, feats, h, c,
                                   hkG, zG, xT2, Hb, captions, d_in[5], syncA);

  gemm_bt<1,true><<<dim3(157,30), 256, 0, stream>>>(Hb, WfcB, bfcB, d_out,
                                                    1920, 10000, 512, syncA);
}